// Round 1
// baseline (162.472 us; speedup 1.0000x reference)
//
#include <hip/hip_runtime.h>
#include <hip/hip_bf16.h>

typedef __attribute__((ext_vector_type(8))) short short8;   // 8 bf16 = 4 VGPRs (MFMA A/B frag)
typedef __attribute__((ext_vector_type(4))) float floatx4;  // MFMA C/D frag
typedef unsigned long long u64;
typedef unsigned int u32;

#define D_DIM 256
#define BN 128
#define BM 128
#define BK 64

// ---------- helpers ----------

__device__ inline unsigned short f2bf_rne(float f) {
  u32 u = __float_as_uint(f);
  u32 r = (u + 0x7FFFu + ((u >> 16) & 1u)) >> 16;
  return (unsigned short)r;
}

// order-preserving float->u32 map, packed with ~idx so that on equal sims the
// SMALLEST index wins under max (matches jnp.argmax first-occurrence).
__device__ inline u64 pack_key(float v, u32 idx) {
  u32 u = __float_as_uint(v);
  u = (u & 0x80000000u) ? ~u : (u | 0x80000000u);
  return ((u64)u << 32) | (u32)(~idx);
}

__device__ inline u64 shfl_xor_u64(u64 x, int d) {
  u32 lo = (u32)__shfl_xor((int)(u32)x, d, 64);
  u32 hi = (u32)__shfl_xor((int)(u32)(x >> 32), d, 64);
  return ((u64)hi << 32) | lo;
}

__device__ inline void async_ld16(const void* g, void* l) {
  __builtin_amdgcn_global_load_lds((const __attribute__((address_space(1))) void*)g,
                                   (__attribute__((address_space(3))) void*)l, 16, 0, 0);
}

// ---------- kernels ----------

__global__ void init_best(u64* __restrict__ p, int n) {
  int i = blockIdx.x * blockDim.x + threadIdx.x;
  if (i < n) p[i] = 0ull;
}

// src: [256][C] f32 (feature-major) -> dst: [C][256] bf16 bits (descriptor-major)
__global__ __launch_bounds__(256) void transpose_cast(const float* __restrict__ src,
                                                      unsigned short* __restrict__ dst, int C) {
  __shared__ float s[64][65];  // +1 pad: conflict-free transpose
  const int tx = threadIdx.x & 63;
  const int ty = threadIdx.x >> 6;  // 0..3
  const int c0 = blockIdx.x * 64;
  const int r0 = blockIdx.y * 64;
  for (int r = ty; r < 64; r += 4)
    s[r][tx] = src[(size_t)(r0 + r) * C + (c0 + tx)];
  __syncthreads();
  for (int r = ty; r < 64; r += 4)
    dst[(size_t)(c0 + r) * D_DIM + (r0 + tx)] = f2bf_rne(s[tx][r]);
}

// Fused sim-GEMM + row/col argmax. At: [N][256] bf16, Bt: [M][256] bf16.
// best01[n] / best10[m] are packed (orderable_sim<<32 | ~idx) u64 maxima.
__global__ __launch_bounds__(256) void gemm_reduce(const unsigned short* __restrict__ At,
                                                   const unsigned short* __restrict__ Bt,
                                                   u64* __restrict__ best01,
                                                   u64* __restrict__ best10) {
  __shared__ alignas(16) unsigned short sA[BN * BK];  // [row][k] 16 KB
  __shared__ alignas(16) unsigned short sB[BM * BK];  // [col][k] 16 KB
  __shared__ u64 ldsRow[BN];
  __shared__ u64 ldsCol[BM];

  const int tid  = threadIdx.x;
  const int wave = tid >> 6;
  const int lane = tid & 63;
  const int quad = lane >> 4;
  const int l15  = lane & 15;
  const int wr   = wave >> 1;  // wave row-half (0..1) -> 64 rows
  const int wc   = wave & 1;   // wave col-half (0..1) -> 64 cols

  const int n0 = blockIdx.x * BN;
  const int m0 = blockIdx.y * BM;

  if (tid < BN) ldsRow[tid] = 0ull;
  else          ldsCol[tid - BN] = 0ull;

  floatx4 acc[4][4];
  for (int i = 0; i < 4; ++i)
    for (int j = 0; j < 4; ++j)
      acc[i][j] = (floatx4){0.f, 0.f, 0.f, 0.f};

  for (int k0 = 0; k0 < D_DIM; k0 += BK) {
    // ---- stage A/B tiles: 1024 x 16B slots each; LDS dest = uniform base + lane*16
    for (int c = 0; c < 4; ++c) {
      const int base_slot = wave * 256 + c * 64;
      const int slot = base_slot + lane;
      const int r  = slot >> 3;       // tile row (0..127)
      const int cc = slot & 7;        // 16B chunk within row
      async_ld16(At + (size_t)(n0 + r) * D_DIM + (k0 + cc * 8), sA + base_slot * 8);
      async_ld16(Bt + (size_t)(m0 + r) * D_DIM + (k0 + cc * 8), sB + base_slot * 8);
    }
    __syncthreads();  // vmcnt(0) drain + barrier

    for (int kc = 0; kc < BK / 32; ++kc) {
      short8 af[4], bfr[4];
      const int kb = kc * 32 + quad * 8;  // lane's k-offset within BK
      for (int t = 0; t < 4; ++t) {
        af[t]  = *(const short8*)(sA + (wr * 64 + t * 16 + l15) * BK + kb);
        bfr[t] = *(const short8*)(sB + (wc * 64 + t * 16 + l15) * BK + kb);
      }
      for (int i = 0; i < 4; ++i)
        for (int j = 0; j < 4; ++j)
          acc[i][j] = __builtin_amdgcn_mfma_f32_16x16x32_bf16(af[i], bfr[j], acc[i][j], 0, 0, 0);
    }
    __syncthreads();  // protect LDS before next-iter overwrite
  }

  // ---- epilogue: C/D mapping (verified): col = lane&15, row = quad*4 + reg
  // row-argmax (over this wave's 64 cols)
  const int mbase = m0 + wc * 64 + l15;
  for (int i = 0; i < 4; ++i) {
    for (int r = 0; r < 4; ++r) {
      float bv = acc[i][0][r];
      u32 bidx = (u32)mbase;
      for (int j = 1; j < 4; ++j) {
        float v = acc[i][j][r];
        if (v > bv) { bv = v; bidx = (u32)(mbase + j * 16); }
      }
      u64 p = pack_key(bv, bidx);
      for (int d = 1; d < 16; d <<= 1) {
        u64 q = shfl_xor_u64(p, d);
        if (q > p) p = q;
      }
      if (l15 == 0) atomicMax(&ldsRow[wr * 64 + i * 16 + quad * 4 + r], p);
    }
  }
  // col-argmax (over this wave's 64 rows)
  const int nbase = n0 + wr * 64 + quad * 4;
  for (int j = 0; j < 4; ++j) {
    float bv = acc[0][j][0];
    u32 bidx = (u32)nbase;
    for (int i = 0; i < 4; ++i)
      for (int r = 0; r < 4; ++r) {
        if (i == 0 && r == 0) continue;
        float v = acc[i][j][r];
        if (v > bv) { bv = v; bidx = (u32)(nbase + i * 16 + r); }
      }
    u64 p = pack_key(bv, bidx);
    u64 q = shfl_xor_u64(p, 16); if (q > p) p = q;
    q = shfl_xor_u64(p, 32);     if (q > p) p = q;
    if (quad == 0) atomicMax(&ldsCol[wc * 64 + j * 16 + l15], p);
  }
  __syncthreads();

  if (tid < BN) atomicMax(&best01[n0 + tid], ldsRow[tid]);
  else          atomicMax(&best10[m0 + (tid - BN)], ldsCol[tid - BN]);
}

__global__ void finalize(const u64* __restrict__ best01, const u64* __restrict__ best10,
                         float* __restrict__ out, int N) {
  int n = blockIdx.x * blockDim.x + threadIdx.x;
  if (n >= N) return;
  u64 p = best01[n];
  u32 key = (u32)(p >> 32);
  u32 sbits = (key & 0x80000000u) ? (key & 0x7FFFFFFFu) : ~key;
  float sim = __uint_as_float(sbits);
  int idx01 = (int)(~(u32)p);
  int idx10 = (int)(~(u32)best10[idx01]);
  float dist = 2.0f - 2.0f * sim;          // squared L2 for unit vectors
  bool ok = (idx10 == n) && (dist <= 0.64f);  // mutual NN + DISTANCE_THRESH^2
  out[n]     = ok ? (float)idx01 : -1.0f;  // matches (written as f32)
  out[N + n] = ok ? (dist + 1.0f) * 0.5f : 0.0f;  // scores
}

// ---------- launcher ----------

extern "C" void kernel_launch(void* const* d_in, const int* in_sizes, int n_in,
                              void* d_out, int out_size, void* d_ws, size_t ws_size,
                              hipStream_t stream) {
  (void)n_in; (void)out_size; (void)ws_size;
  const float* d0 = (const float*)d_in[0];  // [256][N]
  const float* d1 = (const float*)d_in[1];  // [256][M]
  const int N = in_sizes[0] / D_DIM;        // 8192
  const int M = in_sizes[1] / D_DIM;        // 8192

  u64* best01 = (u64*)d_ws;                 //  N u64
  u64* best10 = best01 + N;                 //  M u64
  unsigned short* At = (unsigned short*)(best10 + M);  // [N][256] bf16
  unsigned short* Bt = At + (size_t)N * D_DIM;         // [M][256] bf16
  float* out = (float*)d_out;

  hipLaunchKernelGGL(init_best, dim3((N + M + 255) / 256), dim3(256), 0, stream,
                     best01, N + M);
  hipLaunchKernelGGL(transpose_cast, dim3(N / 64, D_DIM / 64), dim3(256), 0, stream, d0, At, N);
  hipLaunchKernelGGL(transpose_cast, dim3(M / 64, D_DIM / 64), dim3(256), 0, stream, d1, Bt, M);
  hipLaunchKernelGGL(gemm_reduce, dim3(N / BN, M / BM), dim3(256), 0, stream,
                     At, Bt, best01, best10);
  hipLaunchKernelGGL(finalize, dim3(N / 256), dim3(256), 0, stream, best01, best10, out, N);
}

// Round 2
// 162.159 us; speedup vs baseline: 1.0019x; 1.0019x over previous
//
#include <hip/hip_runtime.h>
#include <hip/hip_bf16.h>

typedef __attribute__((ext_vector_type(8))) short short8;   // 8 bf16 = 4 VGPRs (MFMA A/B frag)
typedef __attribute__((ext_vector_type(4))) float floatx4;  // MFMA C/D frag
typedef unsigned long long u64;
typedef unsigned int u32;

#define D_DIM 256
#define BN 128
#define BM 128
#define BK 64
#define GM 4   // m-tiles per block (row-argmax amortization)

// ---------- helpers ----------

__device__ inline unsigned short f2bf_rne(float f) {
  u32 u = __float_as_uint(f);
  u32 r = (u + 0x7FFFu + ((u >> 16) & 1u)) >> 16;
  return (unsigned short)r;
}

// order-preserving float->u32 map, packed with ~idx so that on equal sims the
// SMALLEST index wins under max (matches jnp.argmax first-occurrence).
__device__ inline u64 pack_key(float v, u32 idx) {
  u32 u = __float_as_uint(v);
  u = (u & 0x80000000u) ? ~u : (u | 0x80000000u);
  return ((u64)u << 32) | (u32)(~idx);
}

__device__ inline u64 shfl_xor_u64(u64 x, int d) {
  u32 lo = (u32)__shfl_xor((int)(u32)x, d, 64);
  u32 hi = (u32)__shfl_xor((int)(u32)(x >> 32), d, 64);
  return ((u64)hi << 32) | lo;
}

__device__ inline void async_ld16(const void* g, void* l) {
  __builtin_amdgcn_global_load_lds((const __attribute__((address_space(1))) void*)g,
                                   (__attribute__((address_space(3))) void*)l, 16, 0, 0);
}

// ---------- kernels ----------

// src: [256][C] f32 -> dst: [C][256] bf16. No LDS: per u, a wave reads 256B
// contiguous; store is one 16B short8 per lane. Also folds best-array init.
__global__ __launch_bounds__(256) void transpose_cast(const float* __restrict__ src,
                                                      unsigned short* __restrict__ dst, int C,
                                                      u64* __restrict__ init_ptr, int init_n) {
  const int tid = threadIdx.x;
  const int d = blockIdx.x * 64 + (tid & 63);   // descriptor index
  const int chunk = blockIdx.y * 4 + (tid >> 6);  // 8-feature chunk, 0..31
  const int f0 = chunk * 8;
  float v[8];
#pragma unroll
  for (int u = 0; u < 8; ++u) v[u] = src[(size_t)(f0 + u) * C + d];
  short8 o;
#pragma unroll
  for (int u = 0; u < 8; ++u) o[u] = (short)f2bf_rne(v[u]);
  *(short8*)(dst + (size_t)d * D_DIM + f0) = o;
  if (init_ptr != nullptr && blockIdx.y == 0) {
    int i = blockIdx.x * 256 + tid;
    if (i < init_n) init_ptr[i] = 0ull;
  }
}

// Fused sim-GEMM + row/col argmax over GM m-tiles per block.
// LDS layout is XOR-swizzled: LDS 16B-slot (r, c) holds global k-chunk c^(r&7)
// of row r, so ds_read_b128 frag reads spread across all 8 bank-quads.
__global__ __launch_bounds__(256) void gemm_reduce(const unsigned short* __restrict__ At,
                                                   const unsigned short* __restrict__ Bt,
                                                   u64* __restrict__ best01,
                                                   u64* __restrict__ best10) {
  __shared__ alignas(16) unsigned short sA[BN * BK];  // 16 KB
  __shared__ alignas(16) unsigned short sB[BM * BK];  // 16 KB
  __shared__ u64 ldsRow[BN];
  __shared__ u64 ldsCol[BM];

  const int tid  = threadIdx.x;
  const int wave = tid >> 6;
  const int lane = tid & 63;
  const int quad = lane >> 4;
  const int l15  = lane & 15;
  const int swz  = l15 & 7;     // rA&7 == rB&7 == l15&7 for all frag rows
  const int wr   = wave >> 1;   // wave row-half (0..1)
  const int wc   = wave & 1;    // wave col-half (0..1)

  const int n0 = blockIdx.x * BN;
  const int mg = blockIdx.y;    // m-group of GM tiles

  if (tid < BN) ldsRow[tid] = 0ull;
  else          ldsCol[tid - BN] = 0ull;

  // running row-argmax carried in registers across the GM m-tiles
  float rbv[16];
  u32   rbi[16];
#pragma unroll
  for (int s = 0; s < 16; ++s) { rbv[s] = -2.0f; rbi[s] = 0u; }

  for (int mt = 0; mt < GM; ++mt) {
    const int m0 = (mg * GM + mt) * BM;

    floatx4 acc[4][4];
#pragma unroll
    for (int i = 0; i < 4; ++i)
#pragma unroll
      for (int j = 0; j < 4; ++j)
        acc[i][j] = (floatx4){0.f, 0.f, 0.f, 0.f};

    for (int k0 = 0; k0 < D_DIM; k0 += BK) {
      // stage: LDS slot (r,cc) <- global chunk cc^(r&7); dest = uniform + lane*16
#pragma unroll
      for (int c = 0; c < 4; ++c) {
        const int base_slot = wave * 256 + c * 64;
        const int slot = base_slot + lane;
        const int r   = slot >> 3;
        const int ccg = (slot & 7) ^ (r & 7);
        async_ld16(At + (size_t)(n0 + r) * D_DIM + (k0 + ccg * 8), sA + base_slot * 8);
        async_ld16(Bt + (size_t)(m0 + r) * D_DIM + (k0 + ccg * 8), sB + base_slot * 8);
      }
      __syncthreads();  // vmcnt drain + barrier

#pragma unroll
      for (int kc = 0; kc < BK / 32; ++kc) {
        short8 af[4], bfr[4];
        const int cA = ((kc * 4 + quad) ^ swz) * 8;  // swizzled chunk, in shorts
#pragma unroll
        for (int t = 0; t < 4; ++t) {
          af[t]  = *(const short8*)(sA + (wr * 64 + t * 16 + l15) * BK + cA);
          bfr[t] = *(const short8*)(sB + (wc * 64 + t * 16 + l15) * BK + cA);
        }
#pragma unroll
        for (int i = 0; i < 4; ++i)
#pragma unroll
          for (int j = 0; j < 4; ++j)
            acc[i][j] = __builtin_amdgcn_mfma_f32_16x16x32_bf16(af[i], bfr[j], acc[i][j], 0, 0, 0);
      }
      __syncthreads();  // protect LDS before next-iter overwrite
    }

    // ---- per-tile epilogue.  C/D mapping: col = lane&15, row = quad*4 + reg
    // row-argmax: fold this tile's 4 cols/lane into the register running best
    const int mbase = m0 + wc * 64 + l15;
#pragma unroll
    for (int i = 0; i < 4; ++i)
#pragma unroll
      for (int r = 0; r < 4; ++r) {
        float bv = acc[i][0][r];
        u32 bidx = (u32)mbase;
#pragma unroll
        for (int j = 1; j < 4; ++j) {
          float v = acc[i][j][r];
          if (v > bv) { bv = v; bidx = (u32)(mbase + j * 16); }
        }
        const int s = i * 4 + r;
        if (bv > rbv[s]) { rbv[s] = bv; rbi[s] = bidx; }
      }

    // col-argmax (per tile): reduce this wave's 16 rows per col, butterfly quads
    const int nbase = n0 + wr * 64 + quad * 4;
#pragma unroll
    for (int j = 0; j < 4; ++j) {
      float bv = acc[0][j][0];
      u32 bidx = (u32)nbase;
#pragma unroll
      for (int i = 0; i < 4; ++i)
#pragma unroll
        for (int r = 0; r < 4; ++r) {
          if (i == 0 && r == 0) continue;
          float v = acc[i][j][r];
          if (v > bv) { bv = v; bidx = (u32)(nbase + i * 16 + r); }
        }
      u64 p = pack_key(bv, bidx);
      u64 q = shfl_xor_u64(p, 16); if (q > p) p = q;
      q = shfl_xor_u64(p, 32);     if (q > p) p = q;
      if (quad == 0) atomicMax(&ldsCol[wc * 64 + j * 16 + l15], p);
    }
    __syncthreads();
    if (tid < BM) {
      u64 g = ldsCol[tid];
      ldsCol[tid] = 0ull;  // re-init for next tile (next k-loop barrier orders it)
      atomicMax(&best10[m0 + tid], g);
    }
    // no extra barrier needed: next tile's first __syncthreads (after staging)
    // orders the re-init before the next epilogue's ldsCol atomics.
  }

  // ---- block-end row reduction (amortized over GM tiles)
#pragma unroll
  for (int i = 0; i < 4; ++i)
#pragma unroll
    for (int r = 0; r < 4; ++r) {
      u64 p = pack_key(rbv[i * 4 + r], rbi[i * 4 + r]);
#pragma unroll
      for (int d = 1; d < 16; d <<= 1) {
        u64 q = shfl_xor_u64(p, d);
        if (q > p) p = q;
      }
      if (l15 == 0) atomicMax(&ldsRow[wr * 64 + i * 16 + quad * 4 + r], p);
    }
  __syncthreads();
  if (tid < BN) atomicMax(&best01[n0 + tid], ldsRow[tid]);
}

__global__ void finalize(const u64* __restrict__ best01, const u64* __restrict__ best10,
                         float* __restrict__ out, int N) {
  int n = blockIdx.x * blockDim.x + threadIdx.x;
  if (n >= N) return;
  u64 p = best01[n];
  u32 key = (u32)(p >> 32);
  u32 sbits = (key & 0x80000000u) ? (key & 0x7FFFFFFFu) : ~key;
  float sim = __uint_as_float(sbits);
  int idx01 = (int)(~(u32)p);
  int idx10 = (int)(~(u32)best10[idx01]);
  float dist = 2.0f - 2.0f * sim;             // squared L2 for unit vectors
  bool ok = (idx10 == n) && (dist <= 0.64f);  // mutual NN + DISTANCE_THRESH^2
  out[n]     = ok ? (float)idx01 : -1.0f;     // matches (written as f32)
  out[N + n] = ok ? (dist + 1.0f) * 0.5f : 0.0f;  // scores
}

// ---------- launcher ----------

extern "C" void kernel_launch(void* const* d_in, const int* in_sizes, int n_in,
                              void* d_out, int out_size, void* d_ws, size_t ws_size,
                              hipStream_t stream) {
  (void)n_in; (void)out_size; (void)ws_size;
  const float* d0 = (const float*)d_in[0];  // [256][N]
  const float* d1 = (const float*)d_in[1];  // [256][M]
  const int N = in_sizes[0] / D_DIM;        // 8192
  const int M = in_sizes[1] / D_DIM;        // 8192

  u64* best01 = (u64*)d_ws;                 //  N u64
  u64* best10 = best01 + N;                 //  M u64
  unsigned short* At = (unsigned short*)(best10 + M);  // [N][256] bf16
  unsigned short* Bt = At + (size_t)N * D_DIM;         // [M][256] bf16
  float* out = (float*)d_out;

  // transpose+cast both inputs; first launch also zero-inits best01/best10
  hipLaunchKernelGGL(transpose_cast, dim3(N / 64, 8), dim3(256), 0, stream,
                     d0, At, N, best01, N + M);
  hipLaunchKernelGGL(transpose_cast, dim3(M / 64, 8), dim3(256), 0, stream,
                     d1, Bt, M, (u64*)nullptr, 0);
  hipLaunchKernelGGL(gemm_reduce, dim3(N / BN, M / (BM * GM)), dim3(256), 0, stream,
                     At, Bt, best01, best10);
  hipLaunchKernelGGL(finalize, dim3(N / 256), dim3(256), 0, stream, best01, best10, out, N);
}

// Round 3
// 120.083 us; speedup vs baseline: 1.3530x; 1.3504x over previous
//
#include <hip/hip_runtime.h>
#include <hip/hip_bf16.h>

typedef __attribute__((ext_vector_type(8))) short short8;   // 8 bf16 (MFMA A/B frag)
typedef __attribute__((ext_vector_type(4))) float floatx4;  // MFMA C/D frag
typedef unsigned int u32;

#define D_DIM 256
#define TCOLS 64      // B-tile width (cols per tile)
#define TILES 16      // tiles per block -> 1024 cols per block
#define IDX_BITS 0x1FFFu      // 13-bit index payload (N=M=8192)
#define VAL_MASK 0xFFFFE000u  // truncated orderable-f32 value

// ---------- helpers ----------

__device__ inline unsigned short f2bf_rne(float f) {
  u32 u = __float_as_uint(f);
  u32 r = (u + 0x7FFFu + ((u >> 16) & 1u)) >> 16;
  return (unsigned short)r;
}

// order-preserving f32 -> u32 (monotone; all values comparable as unsigned)
__device__ inline u32 fmap(float v) {
  u32 u = __float_as_uint(v);
  return u ^ (((u32)((int)u >> 31)) | 0x80000000u);
}

__device__ inline u32 umax(u32 a, u32 b) { return a > b ? a : b; }

__device__ inline void async_ld16(const void* g, void* l) {
  __builtin_amdgcn_global_load_lds((const __attribute__((address_space(1))) void*)g,
                                   (__attribute__((address_space(3))) void*)l, 16, 0, 0);
}

// ---------- kernels ----------

// Both inputs: [256][8192] f32 -> [8192][256] bf16; z selects input.
// Coalesced 256B reads per wave, 16B short8 stores. Folds best-array init.
__global__ __launch_bounds__(256) void transpose_cast(const float* __restrict__ d0,
                                                      const float* __restrict__ d1,
                                                      unsigned short* __restrict__ At,
                                                      unsigned short* __restrict__ Bt,
                                                      int C, u32* __restrict__ best, int init_n) {
  const float* src = blockIdx.z ? d1 : d0;
  unsigned short* dst = blockIdx.z ? Bt : At;
  const int tid = threadIdx.x;
  const int d = blockIdx.x * 64 + (tid & 63);     // descriptor index
  const int chunk = blockIdx.y * 4 + (tid >> 6);  // 8-feature chunk, 0..31
  const int f0 = chunk * 8;
  float v[8];
#pragma unroll
  for (int u = 0; u < 8; ++u) v[u] = src[(size_t)(f0 + u) * C + d];
  short8 o;
#pragma unroll
  for (int u = 0; u < 8; ++u) o[u] = (short)f2bf_rne(v[u]);
  *(short8*)(dst + (size_t)d * D_DIM + f0) = o;
  if (blockIdx.z == 0 && blockIdx.y == 0) {
    int i = blockIdx.x * 256 + tid;  // 128 blocks x 256 = 32768 >= 16384
    if (i < init_n) best[i] = 0u;
  }
}

// Full-K-in-registers GEMM + fused argmax.
// Block: 256 rows (4 waves x 64), 16 tiles x 64 cols. A frags live in VGPRs
// (32 short8 = 128 VGPRs / lane); LDS holds only B, double-buffered.
// B LDS is XOR-swizzled on the low-3 chunk bits to kill bank conflicts.
__global__ __launch_bounds__(256, 1) void gemm_reduce(const unsigned short* __restrict__ At,
                                                      const unsigned short* __restrict__ Bt,
                                                      u32* __restrict__ best01,
                                                      u32* __restrict__ best10) {
  __shared__ alignas(16) unsigned short sB[2][TCOLS * D_DIM];  // 2 x 32 KB
  __shared__ u32 ldsCol[TCOLS];

  const int tid  = threadIdx.x;
  const int wave = tid >> 6;
  const int lane = tid & 63;
  const int quad = lane >> 4;
  const int l15  = lane & 15;
  const int n0   = blockIdx.x * 256;
  const int mg0  = blockIdx.y * (TILES * TCOLS);
  const int rbase = n0 + wave * 64;

  if (tid < TCOLS) ldsCol[tid] = 0u;

  // stage B tile 0 into buf 0 (LDS dest = uniform base + tid*16 — required)
  {
    const unsigned short* src = Bt + (size_t)mg0 * D_DIM;
#pragma unroll
    for (int c = 0; c < 8; ++c) {
      int slot = c * 256 + tid;
      int r = slot >> 5, cc = slot & 31;
      int ccg = (cc & 24) | ((cc ^ r) & 7);
      async_ld16(src + (size_t)r * D_DIM + ccg * 8, (unsigned short*)sB[0] + slot * 8);
    }
  }

  // A fragments: wave's 64 rows x full K=256, straight from global.
  // For fixed (t,kc): 16 rows x 64 contiguous bytes -> fully-used cache lines.
  short8 af[4][8];
#pragma unroll
  for (int t = 0; t < 4; ++t)
#pragma unroll
    for (int kc = 0; kc < 8; ++kc)
      af[t][kc] = *(const short8*)(At + (size_t)(rbase + t * 16 + l15) * D_DIM + kc * 32 + quad * 8);

  u32 rbk[16];  // running row-argmax keys (16 rows per lane)
#pragma unroll
  for (int s = 0; s < 16; ++s) rbk[s] = 0u;

  __syncthreads();  // drains vmcnt: B0 staged; ldsCol init visible

  for (int mt = 0; mt < TILES; ++mt) {
    const int m0 = mg0 + mt * TCOLS;
    if (mt + 1 < TILES) {  // prefetch next B tile — latency hides under MFMA
      const unsigned short* src = Bt + (size_t)(m0 + TCOLS) * D_DIM;
      unsigned short* dstb = (unsigned short*)sB[(mt + 1) & 1];
#pragma unroll
      for (int c = 0; c < 8; ++c) {
        int slot = c * 256 + tid;
        int r = slot >> 5, cc = slot & 31;
        int ccg = (cc & 24) | ((cc ^ r) & 7);
        async_ld16(src + (size_t)r * D_DIM + ccg * 8, dstb + slot * 8);
      }
    }

    floatx4 acc[4][4];
#pragma unroll
    for (int i = 0; i < 4; ++i)
#pragma unroll
      for (int j = 0; j < 4; ++j)
        acc[i][j] = (floatx4){0.f, 0.f, 0.f, 0.f};

    const unsigned short* sb = (const unsigned short*)sB[mt & 1];
#pragma unroll
    for (int kc = 0; kc < 8; ++kc) {
      short8 bfr[4];
#pragma unroll
      for (int j = 0; j < 4; ++j) {
        int c2 = j * 16 + l15;
        int ch = kc * 4 + quad;
        int chg = (ch & 24) | ((ch ^ c2) & 7);  // un-swizzle
        bfr[j] = *(const short8*)(sb + c2 * D_DIM + chg * 8);
      }
#pragma unroll
      for (int i = 0; i < 4; ++i)
#pragma unroll
        for (int j = 0; j < 4; ++j)
          acc[i][j] = __builtin_amdgcn_mfma_f32_16x16x32_bf16(af[i][kc], bfr[j], acc[i][j], 0, 0, 0);
    }

    // ---- epilogue. C/D map: col = j*16 + l15, row = i*16 + quad*4 + r
    u32 cb[4] = {0u, 0u, 0u, 0u};
    u32 colpay[4];
#pragma unroll
    for (int j = 0; j < 4; ++j) colpay[j] = (~(u32)(m0 + j * 16 + l15)) & IDX_BITS;
#pragma unroll
    for (int i = 0; i < 4; ++i)
#pragma unroll
      for (int r = 0; r < 4; ++r) {
        u32 rowpay = (~(u32)(rbase + i * 16 + quad * 4 + r)) & IDX_BITS;
        u32 rb = rbk[i * 4 + r];
#pragma unroll
        for (int j = 0; j < 4; ++j) {
          u32 u = fmap(acc[i][j][r]) & VAL_MASK;
          rb = umax(rb, u | colpay[j]);
          cb[j] = umax(cb[j], u | rowpay);
        }
        rbk[i * 4 + r] = rb;
      }
    // col-argmax: butterfly over the 4 quads (rows), then LDS combine
#pragma unroll
    for (int j = 0; j < 4; ++j) {
      u32 b = cb[j];
      b = umax(b, (u32)__shfl_xor((int)b, 16, 64));
      b = umax(b, (u32)__shfl_xor((int)b, 32, 64));
      if (quad == 0) atomicMax(&ldsCol[j * 16 + l15], b);
    }
    __syncthreads();  // col atomics done; also drains vmcnt -> next B ready
    if (tid < TCOLS) {
      u32 g = ldsCol[tid];
      ldsCol[tid] = 0u;
      atomicMax(&best10[m0 + tid], g);
    }
    __syncthreads();  // reset visible before next tile's epilogue
  }

  // ---- final row reduction: butterfly over l15, one atomic per row
#pragma unroll
  for (int i = 0; i < 4; ++i)
#pragma unroll
    for (int r = 0; r < 4; ++r) {
      u32 b = rbk[i * 4 + r];
      b = umax(b, (u32)__shfl_xor((int)b, 1, 64));
      b = umax(b, (u32)__shfl_xor((int)b, 2, 64));
      b = umax(b, (u32)__shfl_xor((int)b, 4, 64));
      b = umax(b, (u32)__shfl_xor((int)b, 8, 64));
      if (l15 == 0) atomicMax(&best01[rbase + i * 16 + quad * 4 + r], b);
    }
}

__global__ void finalize(const u32* __restrict__ best01, const u32* __restrict__ best10,
                         float* __restrict__ out, int N) {
  int n = blockIdx.x * blockDim.x + threadIdx.x;
  if (n >= N) return;
  u32 k = best01[n];
  int idx01 = (int)((~k) & IDX_BITS);
  u32 u = k & VAL_MASK;
  u32 bits = (u & 0x80000000u) ? (u & 0x7FFFFFFFu) : ~u;  // inverse fmap
  float sim = __uint_as_float(bits);
  int idx10 = (int)((~best10[idx01]) & IDX_BITS);
  float dist = 2.0f - 2.0f * sim;             // squared L2 for unit vectors
  bool ok = (idx10 == n) && (dist <= 0.64f);  // mutual NN + thresh^2
  out[n]     = ok ? (float)idx01 : -1.0f;
  out[N + n] = ok ? 1.5f - sim : 0.0f;        // (dist+1)/2
}

// ---------- launcher ----------

extern "C" void kernel_launch(void* const* d_in, const int* in_sizes, int n_in,
                              void* d_out, int out_size, void* d_ws, size_t ws_size,
                              hipStream_t stream) {
  (void)n_in; (void)out_size; (void)ws_size;
  const float* d0 = (const float*)d_in[0];  // [256][N]
  const float* d1 = (const float*)d_in[1];  // [256][M]
  const int N = in_sizes[0] / D_DIM;        // 8192
  const int M = in_sizes[1] / D_DIM;        // 8192

  u32* best01 = (u32*)d_ws;                            // N u32
  u32* best10 = best01 + N;                            // M u32
  unsigned short* At = (unsigned short*)(best10 + M);  // [N][256] bf16
  unsigned short* Bt = At + (size_t)N * D_DIM;         // [M][256] bf16
  float* out = (float*)d_out;

  hipLaunchKernelGGL(transpose_cast, dim3(N / 64, 8, 2), dim3(256), 0, stream,
                     d0, d1, At, Bt, N, best01, N + M);
  hipLaunchKernelGGL(gemm_reduce, dim3(N / 256, M / (TILES * TCOLS)), dim3(256), 0, stream,
                     At, Bt, best01, best10);
  hipLaunchKernelGGL(finalize, dim3(N / 256), dim3(256), 0, stream, best01, best10, out, N);
}